// Round 9
// baseline (1885.844 us; speedup 1.0000x reference)
//
#include <hip/hip_runtime.h>
#include <cstddef>
#include <cstdint>

constexpr int NB = 256;
constexpr int NT = 512;
constexpr int NV = 32;

typedef _Float16 h2_t __attribute__((ext_vector_type(2)));

__device__ __forceinline__ float sigmoidf_(float x){ return 1.0f/(1.0f+__expf(-x)); }
__device__ __forceinline__ float tanhf_(float x){ return 1.0f - 2.0f/(__expf(2.0f*x)+1.0f); }

__device__ __forceinline__ uint32_t pack2u_(float a, float b){
  h2_t r; r.x=(_Float16)a; r.y=(_Float16)b; return __builtin_bit_cast(uint32_t, r);
}
__device__ __forceinline__ float dot2u_(uint32_t u, uint32_t w, float c){
#if __has_builtin(__builtin_amdgcn_fdot2)
  return __builtin_amdgcn_fdot2(__builtin_bit_cast(h2_t,u), __builtin_bit_cast(h2_t,w), c, false);
#else
  h2_t a=__builtin_bit_cast(h2_t,u), b=__builtin_bit_cast(h2_t,w);
  return c + (float)a.x*(float)b.x + (float)a.y*(float)b.y;
#endif
}
__device__ __forceinline__ float h2f_(unsigned short u){
  _Float16 hv = __builtin_bit_cast(_Float16, u); return (float)hv;
}
__device__ __forceinline__ unsigned short f2h_(float a){
  _Float16 hv = (_Float16)a; return __builtin_bit_cast(unsigned short, hv);
}

#define Q4(acc, Wv, Uv) { acc=dot2u_((Uv).x,(Wv).x,acc); acc=dot2u_((Uv).y,(Wv).y,acc); \
                          acc=dot2u_((Uv).z,(Wv).z,acc); acc=dot2u_((Uv).w,(Wv).w,acc); }

// ---------------- stats + x_comp ----------------
__global__ __launch_bounds__(256) void k_stats(
    const float* __restrict__ values, const float* __restrict__ masks,
    const int* __restrict__ lengths,
    float* __restrict__ x_comp, float* __restrict__ stats)
{
  const int b = blockIdx.x;
  const int v = threadIdx.x & 31;
  const int g = threadIdx.x >> 5;
  const int len = lengths[b];
  const float* vb = values + (size_t)b*NT*NV;
  const float* mb = masks  + (size_t)b*NT*NV;
  float* xb = x_comp + (size_t)b*NT*NV;
  float s_m=0.f, s_mv=0.f, s_v=0.f, s_v2=0.f;
  for (int t=g; t<NT; t+=8){
    float val = vb[t*NV+v];
    float m   = mb[t*NV+v];
    float xp  = (t==0) ? vb[v] : vb[(t-1)*NV+v];
    float pm  = (t<len) ? 1.0f : 0.0f;
    xb[t*NV+v] = (m*val + (1.0f-m)*xp)*pm;
    s_m += m; s_mv += m*val; s_v += val; s_v2 += val*val;
  }
  __shared__ float red[4][8][32];
  red[0][g][v]=s_m; red[1][g][v]=s_mv; red[2][g][v]=s_v; red[3][g][v]=s_v2;
  __syncthreads();
  if (g==0){
    float a0=0,a1=0,a2=0,a3=0;
    #pragma unroll
    for(int i=0;i<8;i++){ a0+=red[0][i][v]; a1+=red[1][i][v]; a2+=red[2][i][v]; a3+=red[3][i][v]; }
    float msum = fmaxf(a0, 1.0f);
    float mean = a1/msum;
    float dss  = a3 - 2.0f*mean*a2 + (float)NT*mean*mean;
    float var  = (msum > 1.0f) ? dss/(msum-1.0f) : 0.0f;
    float sd   = sqrtf(fmaxf(var, 0.0f));
    float miss = 1.0f - a0 / fmaxf((float)len, 1.0f);
    float* st = stats + b*97;
    if (v==0) st[0] = (float)len;
    st[1+v]=mean; st[33+v]=sd; st[65+v]=miss;
  }
}

// ---------------- context MLP ----------------
__global__ __launch_bounds__(64) void k_cmlp(
    const float* __restrict__ stats,
    const float* __restrict__ W1, const float* __restrict__ b1,
    const float* __restrict__ W2, const float* __restrict__ b2,
    float* __restrict__ ctx)
{
  const int b = blockIdx.x;
  const int j = threadIdx.x;
  __shared__ float st[97];
  __shared__ float hm[64];
  for (int k=j; k<97; k+=64) st[k] = stats[b*97+k];
  __syncthreads();
  float a0=b1[j], a1=0.f, a2=0.f, a3=0.f;
  #pragma unroll
  for (int k=0; k<96; k+=4){
    a0 += st[k]*W1[j*97+k];     a1 += st[k+1]*W1[j*97+k+1];
    a2 += st[k+2]*W1[j*97+k+2]; a3 += st[k+3]*W1[j*97+k+3];
  }
  a0 += st[96]*W1[j*97+96];
  hm[j] = fmaxf((a0+a1)+(a2+a3), 0.0f);
  __syncthreads();
  if (j < 32){
    float c0_=b2[j], c1=0.f, c2=0.f, c3=0.f;
    #pragma unroll
    for (int k=0;k<64;k+=4){
      c0_ += hm[k]*W2[j*64+k];    c1 += hm[k+1]*W2[j*64+k+1];
      c2 += hm[k+2]*W2[j*64+k+2]; c3 += hm[k+3]*W2[j*64+k+3];
    }
    ctx[b*64+j] = (c0_+c1)+(c2+c3);
  }
}

// ---------------- GRU x-part GEMM: gi[b*T][96] f16 = [x,rf,rb]@Wih^T + bih ----------------
__global__ __launch_bounds__(128) void k_gigru(
    const float* __restrict__ x_comp, const float* __restrict__ rain_f,
    const float* __restrict__ rain_b,
    const float* __restrict__ Wih, const float* __restrict__ bih,
    unsigned short* __restrict__ gig)
{
  __shared__ uint32_t WT[48][98];
  __shared__ __align__(16) uint32_t us[8][48];
  const int tid = threadIdx.x;
  for (int idx = tid; idx < 48*96; idx += 128){
    const int k = idx / 96, col = idx - k*96;
    WT[k][col] = pack2u_(Wih[(size_t)col*96 + 2*k], Wih[(size_t)col*96 + 2*k + 1]);
  }
  const float bias = (tid < 96) ? bih[tid] : 0.f;
  __syncthreads();
  const int NR = NB*NT;
  for (int r0 = blockIdx.x*8; r0 < NR; r0 += gridDim.x*8){
    __syncthreads();
    for (int idx = tid; idx < 8*48; idx += 128){
      const int r = idx / 48, w = idx - r*48;
      const size_t row = (size_t)r0 + r;
      const int i0 = 2*w, i1 = 2*w+1;
      const float a = (i0<32)? x_comp[row*32+i0] : (i0<64 ? rain_f[row*32+i0-32] : rain_b[row*32+i0-64]);
      const float c = (i1<32)? x_comp[row*32+i1] : (i1<64 ? rain_f[row*32+i1-32] : rain_b[row*32+i1-64]);
      us[r][w] = pack2u_(a, c);
    }
    __syncthreads();
    if (tid < 96){
      #pragma unroll
      for (int r=0;r<8;r++){
        const uint4* U = (const uint4*)us[r];
        float acc = bias;
        #pragma unroll
        for (int k4=0;k4<12;k4++){
          const uint4 u4 = U[k4];
          acc = dot2u_(u4.x, WT[4*k4][tid],   acc);
          acc = dot2u_(u4.y, WT[4*k4+1][tid], acc);
          acc = dot2u_(u4.z, WT[4*k4+2][tid], acc);
          acc = dot2u_(u4.w, WT[4*k4+3][tid], acc);
        }
        gig[((size_t)r0+r)*96 + tid] = f2h_(acc);
      }
    }
  }
}

// ---------------- GRU scan: 1 wave = 2 batch chains, lane-local combine ----------------
__global__ __launch_bounds__(64) void k_gru(
    const unsigned short* __restrict__ gig, const int* __restrict__ lengths,
    const float* __restrict__ Whh, const float* __restrict__ bhh,
    float* __restrict__ ctx)
{
  __shared__ uint32_t wh[96*20];          // [gate][16 packed + pad4]
  __shared__ __align__(16) uint32_t hpk[2][16];
  const int lane = threadIdx.x;
  const int half = lane >> 5, l = lane & 31;
  const int b = blockIdx.x*2 + half;
  for (int idx = lane; idx < 96*16; idx += 64){
    const int g = idx >> 4, k = idx & 15;
    wh[g*20+k] = pack2u_(Whh[g*32+2*k], Whh[g*32+2*k+1]);
  }
  const float bh_r = bhh[l], bh_z = bhh[32+l], bh_n = bhh[64+l];
  int len = lengths[b]; if (len > NT) len = NT;
  const int lenO = __shfl_xor(len, 32);
  const int lmax = (len > lenO) ? len : lenO;
  float h = 0.f;
  if (!(l&1)) hpk[half][l>>1] = 0u;
  const unsigned short* gp = gig + (size_t)b*NT*96;
  float gir=0.f, giz=0.f, gin=0.f;
  if (lmax > 0){ gir = h2f_(gp[l]); giz = h2f_(gp[32+l]); gin = h2f_(gp[64+l]); }
  __syncthreads();
  #define GATEG(acc, g) { const uint4* W4 = (const uint4*)(wh + (size_t)(g)*20); \
    const uint4 w0_=W4[0], w1_=W4[1], w2_=W4[2], w3_=W4[3]; \
    Q4(acc,w0_,H0) Q4(acc,w1_,H1) Q4(acc,w2_,H2) Q4(acc,w3_,H3) }
  for (int t=0; t<lmax; ++t){
    float nr=0.f, nz=0.f, nn=0.f;
    if (t+1 < lmax){
      const unsigned short* gn = gp + (size_t)(t+1)*96;
      nr = h2f_(gn[l]); nz = h2f_(gn[32+l]); nn = h2f_(gn[64+l]);
    }
    const uint4* hp4 = (const uint4*)hpk[half];
    const uint4 H0=hp4[0], H1=hp4[1], H2=hp4[2], H3=hp4[3];
    float ar=bh_r, az=bh_z, an=bh_n;
    GATEG(ar, l) GATEG(az, 32+l) GATEG(an, 64+l)
    if (t < len){
      const float r = sigmoidf_(gir + ar);
      const float z = sigmoidf_(giz + az);
      const float n = tanhf_(gin + r*an);
      h = (1.0f - z)*n + z*h;
    }
    gir=nr; giz=nz; gin=nn;
    const float hpr = __shfl_xor(h, 1);
    if (!(l&1)) hpk[half][l>>1] = pack2u_(h, hpr);
    __syncthreads();
  }
  #undef GATEG
  ctx[b*64 + 32 + l] = h;
}

// ---------------- init: h0/c0, ctx-part of LSTM gates, hidden seeds ----------------
__global__ __launch_bounds__(256) void k_init(
    const float* __restrict__ ctx,
    const float* __restrict__ initW, const float* __restrict__ initb,
    const float* __restrict__ WihF, const float* __restrict__ bihF, const float* __restrict__ bhhF,
    const float* __restrict__ WihB, const float* __restrict__ bihB, const float* __restrict__ bhhB,
    float* __restrict__ h0, float* __restrict__ c0,
    float* __restrict__ cgF, float* __restrict__ cgB,
    float* __restrict__ hidden)
{
  const int b = blockIdx.x;
  const int j = threadIdx.x;
  __shared__ __align__(16) float cv[64];
  if (j < 64) cv[j] = ctx[b*64+j];
  __syncthreads();
  {
    float4 f = {bihF[j]+bhhF[j], 0.f, 0.f, 0.f};
    float4 g = {bihB[j]+bhhB[j], 0.f, 0.f, 0.f};
    #pragma unroll
    for (int q=0;q<16;q++){
      const float4 cvv = *(const float4*)&cv[4*q];
      const float4 wf = *(const float4*)(WihF + (size_t)j*128 + 64 + 4*q);
      const float4 wb = *(const float4*)(WihB + (size_t)j*128 + 64 + 4*q);
      f.x += cvv.x*wf.x; f.y += cvv.y*wf.y; f.z += cvv.z*wf.z; f.w += cvv.w*wf.w;
      g.x += cvv.x*wb.x; g.y += cvv.y*wb.y; g.z += cvv.z*wb.z; g.w += cvv.w*wb.w;
    }
    cgF[b*256+j] = (f.x+f.y)+(f.z+f.w);
    cgB[b*256+j] = (g.x+g.y)+(g.z+g.w);
  }
  if (j < 128){
    float4 a = {initb[j], 0.f, 0.f, 0.f};
    #pragma unroll
    for (int q=0;q<16;q++){
      const float4 cvv = *(const float4*)&cv[4*q];
      const float4 w  = *(const float4*)(initW + (size_t)j*64 + 4*q);
      a.x += cvv.x*w.x; a.y += cvv.y*w.y; a.z += cvv.z*w.z; a.w += cvv.w*w.w;
    }
    float hv = (a.x+a.y)+(a.z+a.w);
    h0[b*128+j] = hv;
    c0[b*128+j] = tanhf_(hv);
    if (j < 64) hidden[(size_t)b*NT*128 + j] = hv;                                // fwd seed t=0
    else        hidden[(size_t)b*NT*128 + (size_t)(NT-1)*128 + 64 + (j-64)] = hv; // bwd seed t=T-1
  }
}

// ---------------- LSTM scan: 1 wave per (b,dir); lane owns h[l]; lane-local combine ----------------
// dyn LDS words: wx[256*36] | wh[256*36] | upk[2*32] | hpk[32]  = 18528 words = 74112 B
__global__ __launch_bounds__(64) void k_lstm(
    const float* __restrict__ x_comp, const float* __restrict__ masks,
    const float* __restrict__ WihF, const float* __restrict__ WhhF,
    const float* __restrict__ WihB, const float* __restrict__ WhhB,
    const float* __restrict__ cgF, const float* __restrict__ cgB,
    const float* __restrict__ h0, const float* __restrict__ c0,
    const int* __restrict__ lengths,
    float* __restrict__ hidden)
{
  extern __shared__ uint32_t lds[];
  uint32_t* wx  = lds;            // [256][36]
  uint32_t* wh  = lds + 9216;     // [256][36]
  uint32_t* upk = lds + 18432;    // [2][32]
  uint32_t* hpk = lds + 18496;    // [32]
  const int b = blockIdx.x;
  const int dir = blockIdx.y;
  const int l = threadIdx.x;      // 0..63
  const float* Wih = dir ? WihB : WihF;
  const float* Whh = dir ? WhhB : WhhF;
  for (int idx = l; idx < 256*32; idx += 64){
    const int g = idx >> 5, k = idx & 31;
    wx[g*36+k] = pack2u_(Wih[(size_t)g*128 + 2*k], Wih[(size_t)g*128 + 2*k+1]);
    wh[g*36+k] = pack2u_(Whh[(size_t)g*64  + 2*k], Whh[(size_t)g*64  + 2*k+1]);
  }
  const float* cgp = (dir ? cgB : cgF) + b*256;
  const float cg0 = cgp[l], cg1 = cgp[64+l], cg2 = cgp[128+l], cg3 = cgp[192+l];
  const int len = lengths[b];
  int nsteps = NT-1;
  if (dir == 0){ int e = len-1; if (e<0) e=0; if (e<nsteps) nsteps=e; }
  const float* xc = x_comp + (size_t)b*NT*NV;
  const float* mk = masks  + (size_t)b*NT*NV;
  float* hout = hidden + (size_t)b*NT*128 + dir*64;
  float h = h0[b*128 + dir*64 + l];
  float c = c0[b*128 + dir*64 + l];
  {
    const float hpr = __shfl_xor(h, 1);
    if (!(l&1)) hpk[l>>1] = pack2u_(h, hpr);
    if (nsteps > 0){
      const int t0 = dir ? NT-1 : 0;
      const float v = (l<32) ? xc[t0*NV + l] : mk[t0*NV + l - 32];
      const float vpr = __shfl_xor(v, 1);
      if (!(l&1)) upk[l>>1] = pack2u_(v, vpr);
    }
  }
  __syncthreads();
  #define GATE(acc, g) { \
    const uint4* Wx4 = (const uint4*)(wx + (size_t)(g)*36); \
    const uint4* Wh4 = (const uint4*)(wh + (size_t)(g)*36); \
    const uint4 a0_=Wx4[0],a1_=Wx4[1],a2_=Wx4[2],a3_=Wx4[3]; \
    const uint4 a4_=Wx4[4],a5_=Wx4[5],a6_=Wx4[6],a7_=Wx4[7]; \
    const uint4 b0_=Wh4[0],b1_=Wh4[1],b2_=Wh4[2],b3_=Wh4[3]; \
    const uint4 b4_=Wh4[4],b5_=Wh4[5],b6_=Wh4[6],b7_=Wh4[7]; \
    Q4(acc,a0_,U0) Q4(acc,a1_,U1) Q4(acc,a2_,U2) Q4(acc,a3_,U3) \
    Q4(acc,a4_,U4) Q4(acc,a5_,U5) Q4(acc,a6_,U6) Q4(acc,a7_,U7) \
    Q4(acc,b0_,H0) Q4(acc,b1_,H1) Q4(acc,b2_,H2) Q4(acc,b3_,H3) \
    Q4(acc,b4_,H4) Q4(acc,b5_,H5) Q4(acc,b6_,H6) Q4(acc,b7_,H7) }
  for (int s=0; s<nsteps; ++s){
    const int cur = s & 1;
    float pf = 0.f;
    const bool dopf = (s+1 < nsteps);
    if (dopf){
      const int tn = dir ? (NT-2-s) : (s+1);
      pf = (l<32) ? xc[tn*NV + l] : mk[tn*NV + l - 32];
    }
    const uint4* up = (const uint4*)(upk + cur*32);
    const uint4 U0=up[0],U1=up[1],U2=up[2],U3=up[3];
    const uint4 U4=up[4],U5=up[5],U6=up[6],U7=up[7];
    const uint4* hp4 = (const uint4*)hpk;
    const uint4 H0=hp4[0],H1=hp4[1],H2=hp4[2],H3=hp4[3];
    const uint4 H4=hp4[4],H5=hp4[5],H6=hp4[6],H7=hp4[7];
    float ai=cg0, af=cg1, ag=cg2, ao=cg3;
    GATE(ai, l) GATE(af, 64+l) GATE(ag, 128+l) GATE(ao, 192+l)
    c = sigmoidf_(af)*c + sigmoidf_(ai)*tanhf_(ag);
    h = sigmoidf_(ao)*tanhf_(c);
    const int t    = dir ? (NT-1-s) : s;
    const int outt = dir ? (t-1)    : (s+1);
    hout[(size_t)outt*128 + l] = h;
    const float hpr = __shfl_xor(h, 1);
    if (!(l&1)) hpk[l>>1] = pack2u_(h, hpr);
    if (dopf){
      const float vpr = __shfl_xor(pf, 1);
      if (!(l&1)) upk[(cur^1)*32 + (l>>1)] = pack2u_(pf, vpr);
    }
    __syncthreads();
  }
  #undef GATE
}

// ---------------- feature-regression: LDS f16 weights, 4 rows/iter ----------------
__global__ __launch_bounds__(512) void k_feat(
    const float* __restrict__ x_comp,
    const float* __restrict__ feat_W, const float* __restrict__ feat_b,
    const float* __restrict__ nl1_W, const float* __restrict__ nl1_b,
    const float* __restrict__ nl2_W, const float* __restrict__ nl2_b,
    float* __restrict__ feat_imp)
{
  extern __shared__ char smem_[];
  uint32_t (*WfT)[1024]   = (uint32_t(*)[1024])(smem_);
  uint32_t (*nl1T)[32]    = (uint32_t(*)[32])(smem_ + 65536);
  uint32_t (*xp)[16]      = (uint32_t(*)[16])(smem_ + 67584);
  uint32_t (*hidp)[32][16]= (uint32_t(*)[32][16])(smem_ + 67840);
  const int tid = threadIdx.x;
  const int lane = tid & 31;
  const int ig = tid >> 5;        // 0..15
  const int i0 = ig, i1 = ig + 16;
  for (int idx = tid; idx < 16*1024; idx += 512){
    const int k = idx >> 10, rr = idx & 1023;
    const int i = rr >> 5;
    float a = feat_W[(size_t)rr*32 + 2*k];
    float c2 = feat_W[(size_t)rr*32 + 2*k + 1];
    if (2*k == i) a = 0.f;
    if (2*k+1 == i) c2 = 0.f;
    WfT[k][rr] = pack2u_(a, c2);
  }
  for (int idx = tid; idx < 16*32; idx += 512){
    const int k = idx >> 5, g = idx & 31;
    nl1T[k][g] = pack2u_(nl1_W[g*32 + 2*k], nl1_W[g*32 + 2*k + 1]);
  }
  const float fb0 = feat_b[i0*32 + lane];
  const float fb1 = feat_b[i1*32 + lane];
  const float n1b = nl1_b[lane];
  const float n2w = nl2_W[lane];
  const float n2b = nl2_b[0];
  __syncthreads();
  const int NQ = (NB*NT)/4;
  for (int rq = blockIdx.x; rq < NQ; rq += gridDim.x){
    const int r = rq*4;
    if (tid < 128){
      const int qq = tid >> 5, v = tid & 31;
      const float xv = x_comp[(size_t)(r+qq)*32 + v];
      const float pr = __shfl_xor(xv, 1);
      if (!(v & 1)) xp[qq][v>>1] = pack2u_(xv, pr);
    }
    __syncthreads();
    uint32_t wa[16], wb[16];
    #pragma unroll
    for (int k=0;k<16;k++){ wa[k] = WfT[k][i0*32+lane]; wb[k] = WfT[k][i1*32+lane]; }
    float za[4], zb[4];
    #pragma unroll
    for (int qq=0;qq<4;qq++){
      const uint4* xq = (const uint4*)xp[qq];
      const uint4 X0=xq[0], X1=xq[1], X2=xq[2], X3=xq[3];
      float s0 = fb0, s1 = fb1;
      s0=dot2u_(X0.x,wa[0],s0);  s1=dot2u_(X0.x,wb[0],s1);
      s0=dot2u_(X0.y,wa[1],s0);  s1=dot2u_(X0.y,wb[1],s1);
      s0=dot2u_(X0.z,wa[2],s0);  s1=dot2u_(X0.z,wb[2],s1);
      s0=dot2u_(X0.w,wa[3],s0);  s1=dot2u_(X0.w,wb[3],s1);
      s0=dot2u_(X1.x,wa[4],s0);  s1=dot2u_(X1.x,wb[4],s1);
      s0=dot2u_(X1.y,wa[5],s0);  s1=dot2u_(X1.y,wb[5],s1);
      s0=dot2u_(X1.z,wa[6],s0);  s1=dot2u_(X1.z,wb[6],s1);
      s0=dot2u_(X1.w,wa[7],s0);  s1=dot2u_(X1.w,wb[7],s1);
      s0=dot2u_(X2.x,wa[8],s0);  s1=dot2u_(X2.x,wb[8],s1);
      s0=dot2u_(X2.y,wa[9],s0);  s1=dot2u_(X2.y,wb[9],s1);
      s0=dot2u_(X2.z,wa[10],s0); s1=dot2u_(X2.z,wb[10],s1);
      s0=dot2u_(X2.w,wa[11],s0); s1=dot2u_(X2.w,wb[11],s1);
      s0=dot2u_(X3.x,wa[12],s0); s1=dot2u_(X3.x,wb[12],s1);
      s0=dot2u_(X3.y,wa[13],s0); s1=dot2u_(X3.y,wb[13],s1);
      s0=dot2u_(X3.z,wa[14],s0); s1=dot2u_(X3.z,wb[14],s1);
      s0=dot2u_(X3.w,wa[15],s0); s1=dot2u_(X3.w,wb[15],s1);
      za[qq] = fmaxf(s0, 0.f); zb[qq] = fmaxf(s1, 0.f);
    }
    #pragma unroll
    for (int qq=0;qq<4;qq++){
      const float pa = __shfl_xor(za[qq], 1);
      const float pb = __shfl_xor(zb[qq], 1);
      if (!(lane & 1)){
        hidp[qq][i0][lane>>1] = pack2u_(za[qq], pa);
        hidp[qq][i1][lane>>1] = pack2u_(zb[qq], pb);
      }
    }
    __syncthreads();
    uint32_t nw[16];
    #pragma unroll
    for (int k=0;k<16;k++) nw[k] = nl1T[k][lane];
    float o[8];
    #pragma unroll
    for (int qq=0;qq<4;qq++){
      const uint4* h0p = (const uint4*)hidp[qq][i0];
      const uint4* h1p = (const uint4*)hidp[qq][i1];
      float s0 = n1b, s1 = n1b;
      #pragma unroll
      for (int c4=0;c4<4;c4++){
        const uint4 H0 = h0p[c4];
        const uint4 H1 = h1p[c4];
        s0=dot2u_(H0.x,nw[4*c4],s0);   s1=dot2u_(H1.x,nw[4*c4],s1);
        s0=dot2u_(H0.y,nw[4*c4+1],s0); s1=dot2u_(H1.y,nw[4*c4+1],s1);
        s0=dot2u_(H0.z,nw[4*c4+2],s0); s1=dot2u_(H1.z,nw[4*c4+2],s1);
        s0=dot2u_(H0.w,nw[4*c4+3],s0); s1=dot2u_(H1.w,nw[4*c4+3],s1);
      }
      o[2*qq]   = fmaxf(s0,0.f)*n2w;
      o[2*qq+1] = fmaxf(s1,0.f)*n2w;
    }
    #pragma unroll
    for (int m=0;m<8;m++){
      #pragma unroll
      for (int off=16; off>0; off>>=1) o[m] += __shfl_xor(o[m], off, 32);
    }
    if (lane == 0){
      #pragma unroll
      for (int qq=0;qq<4;qq++){
        feat_imp[(size_t)(r+qq)*32 + i0] = o[2*qq]   + n2b;
        feat_imp[(size_t)(r+qq)*32 + i1] = o[2*qq+1] + n2b;
      }
    }
    __syncthreads();
  }
}

// ---------------- rnn_imp GEMM + fuse + final: LDS f16 rimp ----------------
__global__ __launch_bounds__(512) void k_final(
    const float* __restrict__ values, const float* __restrict__ masks,
    const float* __restrict__ feat_imp, const float* __restrict__ hidden,
    const float* __restrict__ rimp_W, const float* __restrict__ rimp_b,
    const float* __restrict__ fuse_W, const float* __restrict__ fuse_b,
    const int* __restrict__ lengths, float* __restrict__ out)
{
  const int tid = threadIdx.x;
  const int v = tid & 31;
  const int grp = (tid >> 5) & 7;
  const int half = tid >> 8;
  __shared__ uint32_t rpT[64][32];
  __shared__ __align__(16) uint32_t hrowp[8][64];
  __shared__ float rpart[8][32];
  __shared__ float bpart[8][32];
  for (int idx = tid; idx < 64*32; idx += 512){
    const int k = idx >> 5, vv = idx & 31;
    rpT[k][vv] = pack2u_(rimp_W[(size_t)vv*128 + 2*k], rimp_W[(size_t)vv*128 + 2*k+1]);
  }
  const float4* F4 = (const float4*)(fuse_W + (size_t)v*64 + 32);
  float fconst = 0.f;
  if (!half){
    fconst = fuse_b[v];
    #pragma unroll
    for (int q=0;q<8;q++){
      const float4 fw = *(const float4*)(fuse_W + (size_t)v*64 + 4*q);
      fconst += (fw.x+fw.y)+(fw.z+fw.w);
    }
  }
  const float rbias = rimp_b[v];
  __syncthreads();
  const int NOCT = (NB*NT)/8;
  for (int oc = blockIdx.x; oc < NOCT; oc += gridDim.x){
    const size_t base = (size_t)oc*8;
    __syncthreads();
    if (tid < 256){
      const float4 hv = ((const float4*)(hidden + base*128))[tid];
      const int row = tid >> 5;
      const int w0 = (tid & 31) << 1;
      hrowp[row][w0]   = pack2u_(hv.x, hv.y);
      hrowp[row][w0+1] = pack2u_(hv.z, hv.w);
    }
    __syncthreads();
    const size_t r = base + grp;
    float a = half ? 0.f : rbias;
    {
      const uint4* hp4 = (const uint4*)&hrowp[grp][half*32];
      #pragma unroll
      for (int c4=0;c4<8;c4++){
        const uint4 H = hp4[c4];
        a = dot2u_(H.x, rpT[half*32 + 4*c4][v],     a);
        a = dot2u_(H.y, rpT[half*32 + 4*c4 + 1][v], a);
        a = dot2u_(H.z, rpT[half*32 + 4*c4 + 2][v], a);
        a = dot2u_(H.w, rpT[half*32 + 4*c4 + 3][v], a);
      }
    }
    if (half){
      rpart[grp][v] = a;
      const float* mrow = masks + r*32;
      float m0=0,m1=0,m2=0,m3=0;
      #pragma unroll
      for (int q=0;q<8;q++){
        const float4 mv = *(const float4*)(mrow + 4*q);
        const float4 fv = F4[q];
        m0 = fmaf(mv.x, fv.x, m0); m1 = fmaf(mv.y, fv.y, m1);
        m2 = fmaf(mv.z, fv.z, m2); m3 = fmaf(mv.w, fv.w, m3);
      }
      bpart[grp][v] = (m0+m1)+(m2+m3);
    }
    __syncthreads();
    if (!half){
      const int bb = (int)(r >> 9);
      const int t  = (int)(r & 511);
      const int len = lengths[bb];
      const float rimp = a + rpart[grp][v];
      const float beta = sigmoidf_(fconst + bpart[grp][v]);
      const float fi = feat_imp[r*32+v];
      const float m  = masks[r*32+v];
      const float val= values[r*32+v];
      const float fz = beta*fi + (1.0f-beta)*rimp;
      const float o = m*val + (1.0f-m)*fz;
      out[r*32+v] = (t < len) ? o : 0.0f;
    }
  }
}

extern "C" void kernel_launch(void* const* d_in, const int* in_sizes, int n_in,
                              void* d_out, int out_size, void* d_ws, size_t ws_size,
                              hipStream_t stream) {
  const float* values   = (const float*)d_in[0];
  const float* masks    = (const float*)d_in[1];
  const float* rain_f   = (const float*)d_in[2];
  const float* rain_b   = (const float*)d_in[3];
  const float* cmlp_W1  = (const float*)d_in[4];
  const float* cmlp_b1  = (const float*)d_in[5];
  const float* cmlp_W2  = (const float*)d_in[6];
  const float* cmlp_b2  = (const float*)d_in[7];
  const float* gru_Wih  = (const float*)d_in[8];
  const float* gru_Whh  = (const float*)d_in[9];
  const float* gru_bih  = (const float*)d_in[10];
  const float* gru_bhh  = (const float*)d_in[11];
  const float* init_W   = (const float*)d_in[12];
  const float* init_b   = (const float*)d_in[13];
  const float* lstmf_Wih= (const float*)d_in[14];
  const float* lstmf_Whh= (const float*)d_in[15];
  const float* lstmf_bih= (const float*)d_in[16];
  const float* lstmf_bhh= (const float*)d_in[17];
  const float* lstmb_Wih= (const float*)d_in[18];
  const float* lstmb_Whh= (const float*)d_in[19];
  const float* lstmb_bih= (const float*)d_in[20];
  const float* lstmb_bhh= (const float*)d_in[21];
  const float* rimp_W   = (const float*)d_in[22];
  const float* rimp_b   = (const float*)d_in[23];
  const float* feat_W   = (const float*)d_in[24];
  const float* feat_b   = (const float*)d_in[25];
  const float* nl1_W    = (const float*)d_in[26];
  const float* nl1_b    = (const float*)d_in[27];
  const float* nl2_W    = (const float*)d_in[28];
  const float* nl2_b    = (const float*)d_in[29];
  const float* fuse_W   = (const float*)d_in[30];
  const float* fuse_b   = (const float*)d_in[31];
  const int*   lengths  = (const int*)d_in[32];
  float* out = (float*)d_out;

  float* ws       = (float*)d_ws;
  float* x_comp   = ws;                                   // B*T*V
  float* stats    = x_comp + (size_t)NB*NT*NV;            // B*97
  float* ctx      = stats + NB*97;                        // B*64
  float* h0       = ctx + NB*64;                          // B*128
  float* c0      = h0 + NB*128;                           // B*128
  float* cgF      = c0 + NB*128;                          // B*256
  float* cgB      = cgF + NB*256;                         // B*256
  float* hidden   = cgB + NB*256;                         // B*T*128
  float* feat_imp = hidden + (size_t)NB*NT*128;           // B*T*V
  unsigned short* gig = (unsigned short*)(feat_imp + (size_t)NB*NT*NV); // B*T*96 f16
  // total ~127 MB

  k_stats<<<NB, 256, 0, stream>>>(values, masks, lengths, x_comp, stats);
  k_gigru<<<1024, 128, 0, stream>>>(x_comp, rain_f, rain_b, gru_Wih, gru_bih, gig);
  k_cmlp<<<NB, 64, 0, stream>>>(stats, cmlp_W1, cmlp_b1, cmlp_W2, cmlp_b2, ctx);
  k_gru<<<NB/2, 64, 0, stream>>>(gig, lengths, gru_Whh, gru_bhh, ctx);
  k_init<<<NB, 256, 0, stream>>>(ctx, init_W, init_b,
                                 lstmf_Wih, lstmf_bih, lstmf_bhh,
                                 lstmb_Wih, lstmb_bih, lstmb_bhh,
                                 h0, c0, cgF, cgB, hidden);
  dim3 lgrid(NB, 2);
  k_lstm<<<lgrid, 64, 74112, stream>>>(x_comp, masks,
                                       lstmf_Wih, lstmf_Whh, lstmb_Wih, lstmb_Whh,
                                       cgF, cgB, h0, c0, lengths, hidden);
  k_feat<<<512, 512, 76032, stream>>>(x_comp, feat_W, feat_b, nl1_W, nl1_b, nl2_W, nl2_b, feat_imp);
  k_final<<<2048, 512, 0, stream>>>(values, masks, feat_imp, hidden,
                                    rimp_W, rimp_b, fuse_W, fuse_b, lengths, out);
}